// Round 9
// baseline (2003.317 us; speedup 1.0000x reference)
//
#include <hip/hip_runtime.h>

// VQ-VAE VectorQuantizer forward + EMA update, MI355X (gfx950).
// R2-R9: fp32-VALU distance GEMM plateaus at 810-975us: FMA floor 437us
//   + LDS-delivery floor ~437us on the co-equal pipe. Structural wall.
// R10/R11: bf16 MFMA filter + exact re-rank (bit-exact by construction):
//   1) cvt z,w -> bf16 fragment-ordered arrays (RNE)
//   2) k_mfma<0>: 32x32x16 bf16 MFMA approx distances; per-(row,chunk) min
//   3) k_minred: thr[row] = m + 0.0334*sqrt(x2*w2max) + 4e-4.
//      Soundness: capture needs thr >= m + 2*E_true. E_true <=
//      2*(2u+u^2)*||x||*||w|| + reorder gamma_255 + 2 epilogue ulps
//      (u=2^-8 bf16 RNE; Cauchy-Schwarz) = 0.0157*sqrt(x2*w2max)+6e-5.
//      Margin dominates 2*E_true for all data => true argmin in set.
//   4) k_mfma<1>: same deterministic MFMA; approx<=thr -> append candidate.
//   5) k_rerank: per candidate, EXACT reference fp32 single-FMA-chain
//      (d=0..255 ascending) + identical epilogue rounding; atomicMin on
//      packed (total-order dist key <<32 | code) == exact (dv,code) lex.
//   A/B frag: row/col=lane&31, k=8*(lane>>5)+e (published CDNA layout;
//   identical staging both operands => k-slot permutation cancels).
//   C/D: col=lane&31, row=(reg&3)+8*(reg>>2)+4*(lane>>5) [HW-verified].
// R11 vs R10: sound 2E threshold (tighter window, ~75K cands expected),
//   CAP 786432 (10x headroom), total-order float key. Layout: list 12-15MB,
//   best64 @15MB (8-aligned).

#define NTOK 16384
#define KC   8192
#define DD   256

#define OFF_Q    0
#define OFF_LOSS 4194304
#define OFF_IDX  4194305
#define OFF_W    4210689
#define OFF_CS   6307841
#define OFF_EMA  6316033

#define DECAY_F  0.99f
#define OMD_F    0.01f
#define EPS_F    1e-5f
#define KEPS_F   0.08192f   // K * eps
#define CAP      786432     // candidate list capacity (~10x expected)

typedef unsigned int u32;
typedef unsigned long long u64;
typedef unsigned short u16;
typedef __attribute__((ext_vector_type(8))) short short8;     // 8 bf16
typedef __attribute__((ext_vector_type(16))) float f32x16;    // MFMA acc

// total-order monotone float->u32 key (handles any sign)
__device__ __forceinline__ u32 fkey(float f) {
    u32 u = __float_as_uint(f);
    return (u & 0x80000000u) ? ~u : (u | 0x80000000u);
}

// ---- numpy-pairwise row squared-norms (n=256): two 128 halves, 8 strided
// accumulators each, butterfly combine — bit-exact vs numpy pairwise sum.
__global__ __launch_bounds__(256) void k_rownorm(const float* __restrict__ a,
                                                 float* __restrict__ outn) {
    const int wave = threadIdx.x >> 6, lane = threadIdx.x & 63;
    const int row  = blockIdx.x * 16 + wave * 4 + (lane >> 4);
    const int p    = lane & 15;
    const int h    = p >> 3, j = p & 7;
    const float* base = a + row * DD + h * 128 + j;
    float v = base[0];
    float r = __fmul_rn(v, v);
    #pragma unroll
    for (int t = 1; t < 16; ++t) {
        v = base[8 * t];
        r = __fadd_rn(r, __fmul_rn(v, v));
    }
    r = __fadd_rn(r, __shfl_xor(r, 1));
    r = __fadd_rn(r, __shfl_xor(r, 2));
    r = __fadd_rn(r, __shfl_xor(r, 4));
    r = __fadd_rn(r, __shfl_xor(r, 8));
    if (p == 0) outn[row] = r;
}

// ---------------- w2max (for the error bound) + zero candidate counter ----
__global__ __launch_bounds__(256) void k_w2max(const float* __restrict__ w2v,
                                               float* __restrict__ w2max,
                                               int* __restrict__ counter) {
    const int t = threadIdx.x;
    float m = 0.0f;
    for (int i = t; i < KC; i += 256) m = fmaxf(m, w2v[i]);
    #pragma unroll
    for (int off = 32; off; off >>= 1) m = fmaxf(m, __shfl_down(m, off, 64));
    __shared__ float ps[4];
    if ((t & 63) == 0) ps[t >> 6] = m;
    __syncthreads();
    if (t == 0) {
        *w2max = fmaxf(fmaxf(ps[0], ps[1]), fmaxf(ps[2], ps[3]));
        *counter = 0;
    }
}

// ---------------- fp32 -> bf16 fragment-ordered conversion -----------------
// frag element t = (rt*16+kt)*64 + l holds in[rt*32 + (l&31)][kt*16 +
// 8*(l>>5) .. +8] as 8 RNE bf16 (16B). Also inits best64 when requested.
__global__ __launch_bounds__(256) void k_cvt(const float* __restrict__ in,
                                             u16* __restrict__ outf, int nrt,
                                             u64* __restrict__ binit, int nbin) {
    const int t = blockIdx.x * 256 + threadIdx.x;
    if (binit && t < nbin) binit[t] = ~0ull;
    if (t >= nrt * 1024) return;
    const int l = t & 63, kt = (t >> 6) & 15, rt = t >> 10;
    const float* src = in + (size_t)(rt * 32 + (l & 31)) * DD
                          + kt * 16 + 8 * (l >> 5);
    u32 p[4];
    #pragma unroll
    for (int e = 0; e < 4; ++e) {
        u32 b0 = __float_as_uint(src[2 * e]);
        u32 b1 = __float_as_uint(src[2 * e + 1]);
        b0 = (b0 + 0x7fffu + ((b0 >> 16) & 1u)) >> 16;   // RNE
        b1 = (b1 + 0x7fffu + ((b1 >> 16) & 1u)) >> 16;
        p[e] = b0 | (b1 << 16);
    }
    *(uint4*)(outf + (size_t)t * 8) = make_uint4(p[0], p[1], p[2], p[3]);
}

// ---------------- MFMA approx-distance pass --------------------------------
// grid 8192: rb = bid&127 (128 rows), cb = bid>>7 (128 codes). Wave wv owns
// row-tile rt = rb*4+wv (32 rows) x 4 code-tiles. K-loop 16 steps of K=16.
// COLLECT=0: per-row min over the 128 codes -> vbuf[cb][row].
// COLLECT=1: approx<=thr[row] -> atomic-append (row<<13|code) to list.
template<int COLLECT>
__global__ __launch_bounds__(256) void k_mfma(
        const u16* __restrict__ zb, const u16* __restrict__ wb,
        const float* __restrict__ x2v, const float* __restrict__ w2v,
        const float* __restrict__ thr, float* __restrict__ vbuf,
        u32* __restrict__ list, int* __restrict__ counter) {
    __shared__ float sx2[128], sw2[128], sthr[128];
    const int tid = threadIdx.x;
    const int l = tid & 63, wv = tid >> 6;
    const int rb = blockIdx.x & 127, cb = blockIdx.x >> 7;
    if (tid < 128) {
        sx2[tid] = x2v[rb * 128 + tid];
        if (COLLECT) sthr[tid] = thr[rb * 128 + tid];
    } else {
        sw2[tid - 128] = w2v[cb * 128 + tid - 128];
    }
    __syncthreads();

    const int rt = rb * 4 + wv;
    const short8* Az = (const short8*)zb + (size_t)rt * 1024 + l;
    const short8* B0 = (const short8*)wb + (size_t)(cb * 4 + 0) * 1024 + l;
    const short8* B1 = (const short8*)wb + (size_t)(cb * 4 + 1) * 1024 + l;
    const short8* B2 = (const short8*)wb + (size_t)(cb * 4 + 2) * 1024 + l;
    const short8* B3 = (const short8*)wb + (size_t)(cb * 4 + 3) * 1024 + l;

    f32x16 acc0 = {}, acc1 = {}, acc2 = {}, acc3 = {};
    #pragma unroll 2
    for (int kt = 0; kt < 16; ++kt) {
        const short8 a  = Az[kt * 64];
        const short8 b0 = B0[kt * 64];
        const short8 b1 = B1[kt * 64];
        const short8 b2 = B2[kt * 64];
        const short8 b3 = B3[kt * 64];
        acc0 = __builtin_amdgcn_mfma_f32_32x32x16_bf16(a, b0, acc0, 0, 0, 0);
        acc1 = __builtin_amdgcn_mfma_f32_32x32x16_bf16(a, b1, acc1, 0, 0, 0);
        acc2 = __builtin_amdgcn_mfma_f32_32x32x16_bf16(a, b2, acc2, 0, 0, 0);
        acc3 = __builtin_amdgcn_mfma_f32_32x32x16_bf16(a, b3, acc3, 0, 0, 0);
    }

    const int c_lane = l & 31;
    #pragma unroll
    for (int r = 0; r < 16; ++r) {
        const int rl = wv * 32 + (r & 3) + 8 * (r >> 2) + 4 * (l >> 5);
        const float x2 = sx2[rl];
        const float d0 = __fadd_rn(__fsub_rn(x2, __fmul_rn(2.0f, acc0[r])),
                                   sw2[c_lane]);
        const float d1 = __fadd_rn(__fsub_rn(x2, __fmul_rn(2.0f, acc1[r])),
                                   sw2[32 + c_lane]);
        const float d2 = __fadd_rn(__fsub_rn(x2, __fmul_rn(2.0f, acc2[r])),
                                   sw2[64 + c_lane]);
        const float d3 = __fadd_rn(__fsub_rn(x2, __fmul_rn(2.0f, acc3[r])),
                                   sw2[96 + c_lane]);
        if (!COLLECT) {
            float mn = fminf(fminf(d0, d1), fminf(d2, d3));
            #pragma unroll
            for (int off = 1; off <= 16; off <<= 1)    // within 32-lane half:
                mn = fminf(mn, __shfl_xor(mn, off, 64)); // halves = diff rows
            if (c_lane == 0)
                vbuf[(size_t)cb * NTOK + rb * 128 + rl] = mn;
        } else {
            const float tv = sthr[rl];
            const u32 rowg = rb * 128 + rl;
            if (d0 <= tv) { int p = atomicAdd(counter, 1);
                if (p < CAP) list[p] = (rowg << 13) | (cb * 128 + c_lane); }
            if (d1 <= tv) { int p = atomicAdd(counter, 1);
                if (p < CAP) list[p] = (rowg << 13) | (cb * 128 + 32 + c_lane); }
            if (d2 <= tv) { int p = atomicAdd(counter, 1);
                if (p < CAP) list[p] = (rowg << 13) | (cb * 128 + 64 + c_lane); }
            if (d3 <= tv) { int p = atomicAdd(counter, 1);
                if (p < CAP) list[p] = (rowg << 13) | (cb * 128 + 96 + c_lane); }
        }
    }
}

// ---------------- thr[row] = min_cb vbuf + sound 2E margin -----------------
__global__ __launch_bounds__(256) void k_minred(const float* __restrict__ vbuf,
                                                const float* __restrict__ x2v,
                                                const float* __restrict__ w2max,
                                                float* __restrict__ thr) {
    const int row = blockIdx.x * 256 + threadIdx.x;
    float m = 1e30f;
    for (int cb = 0; cb < 64; ++cb)
        m = fminf(m, vbuf[(size_t)cb * NTOK + row]);
    // 2*E_true <= 0.0315*sqrt(x2*w2max) + 1.3e-4  (see header derivation)
    thr[row] = m + (0.0334f * sqrtf(x2v[row] * (*w2max)) + 4e-4f);
}

// ---------------- exact re-rank of candidates ------------------------------
// One wave per candidate: lanes cooperatively hold z-row/w-row (float4 each);
// all lanes redundantly run the EXACT ascending single-FMA chain via shfl
// broadcast; lane 0 atomicMin's packed (key(dv)<<32|code) per row.
__global__ __launch_bounds__(256) void k_rerank(
        const float* __restrict__ z, const float* __restrict__ w,
        const float* __restrict__ x2v, const float* __restrict__ w2v,
        const u32* __restrict__ list, const int* __restrict__ counter,
        u64* __restrict__ best) {
    const int l = threadIdx.x & 63, wv = threadIdx.x >> 6;
    const int cnt = min(*counter, CAP);
    const int stride = gridDim.x * 4;
    for (int c = blockIdx.x * 4 + wv; c < cnt; c += stride) {
        const u32 e = list[c];
        const int row = e >> 13, col = e & 8191;
        const float4 va = *(const float4*)(z + (size_t)row * DD + l * 4);
        const float4 vb = *(const float4*)(w + (size_t)col * DD + l * 4);
        float xe = 0.0f;
        for (int d4 = 0; d4 < 64; ++d4) {      // d = 4*d4 + {0,1,2,3} asc
            xe = __fmaf_rn(__shfl(va.x, d4), __shfl(vb.x, d4), xe);
            xe = __fmaf_rn(__shfl(va.y, d4), __shfl(vb.y, d4), xe);
            xe = __fmaf_rn(__shfl(va.z, d4), __shfl(vb.z, d4), xe);
            xe = __fmaf_rn(__shfl(va.w, d4), __shfl(vb.w, d4), xe);
        }
        const float dv = __fadd_rn(
            __fsub_rn(x2v[row], __fmul_rn(2.0f, xe)), w2v[col]);
        if (l == 0)
            atomicMin(best + row, ((u64)fkey(dv) << 32) | (u64)(u32)col);
    }
}

// ---------------- extract idx + init EMA outputs + zero loss ---------------
__global__ __launch_bounds__(256) void k_init(const float* __restrict__ emaw,
                                              const float* __restrict__ ecs,
                                              float* __restrict__ out,
                                              float* __restrict__ lossacc,
                                              const u64* __restrict__ best,
                                              int* __restrict__ idx_ws) {
    const int i = blockIdx.x * 256 + threadIdx.x;    // grid covers KC*DD = 2M
    if (i < NTOK) {
        const int code = (int)(best[i] & 8191ull);
        idx_ws[i] = code;
        out[OFF_IDX + i] = (float)code;
    }
    out[OFF_EMA + i] = __fmul_rn(DECAY_F, emaw[i]);
    if (i < KC) out[OFF_CS + i] = __fmul_rn(DECAY_F, ecs[i]);
    if (i == 0) *lossacc = 0.0f;
}

// ---------------- gather quantized + loss partial + EMA scatter ------------
__global__ __launch_bounds__(256) void k_scatter(const float* __restrict__ z,
                                                 const float* __restrict__ w,
                                                 const int* __restrict__ idx_ws,
                                                 float* __restrict__ out,
                                                 float* __restrict__ lossacc) {
    const int n = blockIdx.x, d = threadIdx.x;
    const int k = idx_ws[n];
    const float zv   = z[n * DD + d];
    const float q    = w[k * DD + d];
    const float diff = __fsub_rn(q, zv);
    out[OFF_Q + n * DD + d] = __fadd_rn(zv, diff);   // straight-through value

    float s = __fmul_rn(diff, diff);
    #pragma unroll
    for (int off = 32; off; off >>= 1) s += __shfl_down(s, off, 64);
    __shared__ float ps[4];
    if ((d & 63) == 0) ps[d >> 6] = s;
    __syncthreads();
    if (d == 0) atomicAdd(lossacc, ps[0] + ps[1] + ps[2] + ps[3]);

    atomicAdd(&out[OFF_EMA + k * DD + d], __fmul_rn(OMD_F, zv));
    if (d == 0) atomicAdd(&out[OFF_CS + k], OMD_F);
}

// ---------------- n = sum(new_cluster_size); finalize loss -----------------
__global__ __launch_bounds__(256) void k_nsum(float* __restrict__ out,
                                              const float* __restrict__ lossacc,
                                              float* __restrict__ nsum) {
    const int t = threadIdx.x;
    float s = 0.0f;
    for (int i = t; i < KC; i += 256) s += out[OFF_CS + i];
    #pragma unroll
    for (int off = 32; off; off >>= 1) s += __shfl_down(s, off, 64);
    __shared__ float ps[4];
    if ((t & 63) == 0) ps[t >> 6] = s;
    __syncthreads();
    if (t == 0) {
        *nsum = ps[0] + ps[1] + ps[2] + ps[3];
        out[OFF_LOSS] = 1.25f * (*lossacc) / 4194304.0f;
    }
}

// ---------------- new_weight = new_ema_w / laplace(cluster_size) -----------
__global__ __launch_bounds__(256) void k_neww(float* __restrict__ out,
                                              const float* __restrict__ nsum) {
    const int k = blockIdx.x, d = threadIdx.x;
    const float n  = *nsum;
    const float cs = __fmul_rn(__fdiv_rn(__fadd_rn(out[OFF_CS + k], EPS_F),
                                         __fadd_rn(n, KEPS_F)), n);
    out[OFF_W + k * DD + d] = __fdiv_rn(out[OFF_EMA + k * DD + d], cs);
}

extern "C" void kernel_launch(void* const* d_in, const int* in_sizes, int n_in,
                              void* d_out, int out_size, void* d_ws, size_t ws_size,
                              hipStream_t stream) {
    const float* z    = (const float*)d_in[0];
    const float* w    = (const float*)d_in[1];
    const float* ecs  = (const float*)d_in[2];
    const float* emaw = (const float*)d_in[3];
    float* out = (float*)d_out;

    // small scratch in ws (~164 KB, same budget that always passed)
    int*   idx_ws  = (int*)d_ws;                       // NTOK ints
    float* x2v     = (float*)d_ws + NTOK;              // NTOK floats
    float* w2v     = x2v + NTOK;                       // KC floats
    float* lossacc = w2v + KC;                         // 1 float
    float* nsum    = lossacc + 1;                      // 1 float
    int*   counter = (int*)(nsum + 1);                 // 1 int
    float* w2max   = (float*)(counter + 1);            // 1 float

    // big scratch inside not-yet-final d_out regions (Q region = 16 MB):
    // zb frag 0-8MB | wb frag 8-12MB | list 12-15MB | best64 @15MB (128KB)
    u16* zb     = (u16*)d_out;                               // byte 0
    u16* wb     = (u16*)((char*)d_out + 8388608);            // byte 8 MB
    u32* list   = (u32*)((char*)d_out + 12582912);           // byte 12 MB
    u64* best64 = (u64*)((char*)d_out + 15728640);           // byte 15 MB
    float* vbuf = out + OFF_EMA;   // 64 x NTOK approx chunk-mins (4 MB)
    float* thr  = out + OFF_W;     // NTOK thresholds (64 KB)

    k_rownorm<<<NTOK / 16, 256, 0, stream>>>(z, x2v);
    k_rownorm<<<KC / 16,   256, 0, stream>>>(w, w2v);
    k_w2max  <<<1,         256, 0, stream>>>(w2v, w2max, counter);
    k_cvt    <<<2048,      256, 0, stream>>>(z, zb, 512, best64, NTOK);
    k_cvt    <<<1024,      256, 0, stream>>>(w, wb, 256, (u64*)0, 0);
    k_mfma<0><<<8192,      256, 0, stream>>>(zb, wb, x2v, w2v, thr, vbuf,
                                             list, counter);
    k_minred <<<NTOK / 256, 256, 0, stream>>>(vbuf, x2v, w2max, thr);
    k_mfma<1><<<8192,      256, 0, stream>>>(zb, wb, x2v, w2v, thr, vbuf,
                                             list, counter);
    k_rerank <<<512,       256, 0, stream>>>(z, w, x2v, w2v, list, counter,
                                             best64);
    k_init   <<<(KC * DD) / 256, 256, 0, stream>>>(emaw, ecs, out, lossacc,
                                                   best64, idx_ws);
    k_scatter<<<NTOK,      256, 0, stream>>>(z, w, idx_ws, out, lossacc);
    k_nsum   <<<1,         256, 0, stream>>>(out, lossacc, nsum);
    k_neww   <<<KC,        256, 0, stream>>>(out, nsum);
}